// Round 6
// baseline (222.557 us; speedup 1.0000x reference)
//
#include <hip/hip_runtime.h>
#include <math.h>

#define B_  32
#define D_  256
#define L_  4096
#define S_  64
#define C3_ 192

#define YSZ    ((size_t)B_ * D_ * L_)   /* 33554432 */
#define HOUTSZ ((size_t)B_ * D_ * S_)   /* 524288  */
#define NCHUNK 8

typedef __attribute__((ext_vector_type(8))) short short8;
typedef __attribute__((ext_vector_type(4))) float f32x4;
typedef unsigned short ushort_t;
typedef unsigned int uint_t;

// hardware bf16 convert (RNE)
__device__ __forceinline__ short f2bf(float f) {
    __bf16 h = (__bf16)f;
    return __builtin_bit_cast(short, h);
}
__device__ __forceinline__ float bf2f(ushort_t u) {
    return __uint_as_float((uint_t)u << 16);
}
__device__ __forceinline__ short8 ld_cvt8(const float* p) {
    const float4* q = reinterpret_cast<const float4*>(p);
    float4 p0 = q[0], p1 = q[1];
    short8 s;
    s[0] = f2bf(p0.x); s[1] = f2bf(p0.y); s[2] = f2bf(p0.z); s[3] = f2bf(p0.w);
    s[4] = f2bf(p1.x); s[5] = f2bf(p1.y); s[6] = f2bf(p1.z); s[7] = f2bf(p1.w);
    return s;
}

// ---------------------------------------------------------------------------
// K0: w_bcdt (192x256 f32) -> fragment-major bf16:
//   wfrag[((step*12 + mi)*64 + lane)*8 + j] = bf16(w[mi*16+(lane&15)]
//                                                  [step*32+(lane>>4)*8+j])
// Each lane's MFMA A-fragment is one contiguous 16-B chunk.
// ---------------------------------------------------------------------------
__global__ __launch_bounds__(256) void k0_wfrag(
    const float* __restrict__ w, ushort_t* __restrict__ wfrag)
{
    int gid  = blockIdx.x * 256 + threadIdx.x;   // 0..6143
    int lane = gid & 63;
    int f    = gid >> 6;                         // 0..95
    int step = f / 12, mi = f - step * 12;
    int o  = mi * 16 + (lane & 15);
    int kk = step * 32 + (lane >> 4) * 8;
    short8 s = ld_cvt8(w + (size_t)o * D_ + kk);
    *(short8*)(wfrag + (size_t)gid * 8) = s;
}

// ---------------------------------------------------------------------------
// K1 (MFMA): pre_bf[b][o][l] = bf16( b_bcdt[o] + sum_d w[o][d] * x[b][d][l] )
// A-frags loaded direct from L2-hot wfrag (no LDS). B (x-transpose) in LDS,
// double-buffered, 1 barrier/step. Side-product: xbf[b][d][l] = bf16(x).
// ---------------------------------------------------------------------------
__global__ __launch_bounds__(256) void k1_bcdt_mfma(
    const float* __restrict__ x, const ushort_t* __restrict__ wfrag,
    const float* __restrict__ bias, ushort_t* __restrict__ out,
    ushort_t* __restrict__ xbf)
{
    __shared__ __align__(16) short B_lds[2][128][40];  // [buf][l][k]
    const int l0 = blockIdx.x * 128;
    const int b  = blockIdx.y;
    const int tid  = threadIdx.x;
    const int lane = tid & 63;
    const int wv   = tid >> 6;
    const int lm   = lane & 15;
    const int kg   = lane >> 4;
    const int lp   = tid & 63;    // staging: l-pair index
    const int kgs  = tid >> 6;    // staging: k-group of 8
    const float* xb = x + (size_t)b * D_ * L_;
    uint_t* xo = (uint_t*)(xbf + (size_t)b * D_ * L_);

    f32x4 acc[12][2];
    #pragma unroll
    for (int mi = 0; mi < 12; ++mi)
        #pragma unroll
        for (int nj = 0; nj < 2; ++nj)
            acc[mi][nj] = (f32x4){0.f, 0.f, 0.f, 0.f};

    auto STAGE = [&](int step, int buf) {
        const int k0 = step * 32;
        const float* xp = xb + (size_t)(k0 + kgs * 8) * L_ + l0 + lp * 2;
        float2 v[8];
        #pragma unroll
        for (int r = 0; r < 8; ++r)
            v[r] = *reinterpret_cast<const float2*>(xp + (size_t)r * L_);
        short8 s0, s1;
        #pragma unroll
        for (int r = 0; r < 8; ++r) { s0[r] = f2bf(v[r].x); s1[r] = f2bf(v[r].y); }
        *(short8*)&B_lds[buf][lp * 2][kgs * 8]     = s0;
        *(short8*)&B_lds[buf][lp * 2 + 1][kgs * 8] = s1;
        // side-write: xbf[d][l0+2lp..+1] as packed 2xbf16 (coalesced dwords)
        #pragma unroll
        for (int r = 0; r < 8; ++r) {
            uint_t pk = (uint_t)(ushort_t)s0[r] | ((uint_t)(ushort_t)s1[r] << 16);
            xo[((size_t)(k0 + kgs * 8 + r) * L_ + l0) / 2 + lp] = pk;
        }
    };

    STAGE(0, 0);
    for (int step = 0; step < 8; ++step) {
        __syncthreads();
        if (step < 7) STAGE(step + 1, (step + 1) & 1);
        const int cb = step & 1;
        short8 bbf[2];
        #pragma unroll
        for (int nj = 0; nj < 2; ++nj)
            bbf[nj] = *(const short8*)&B_lds[cb][wv * 32 + nj * 16 + lm][kg * 8];
        const ushort_t* wf = wfrag + ((size_t)step * 12 * 64 + lane) * 8;
        #pragma unroll
        for (int mi = 0; mi < 12; ++mi) {
            short8 a = *(const short8*)(wf + (size_t)mi * 64 * 8);
            #pragma unroll
            for (int nj = 0; nj < 2; ++nj)
                acc[mi][nj] = __builtin_amdgcn_mfma_f32_16x16x32_bf16(
                    a, bbf[nj], acc[mi][nj], 0, 0, 0);
        }
    }
    ushort_t* ob = out + (size_t)b * C3_ * L_;
    const int col = l0 + wv * 32 + lm;
    #pragma unroll
    for (int mi = 0; mi < 12; ++mi) {
        #pragma unroll
        for (int r = 0; r < 4; ++r) {
            int o = mi * 16 + kg * 4 + r;
            float bv = bias[o];
            #pragma unroll
            for (int nj = 0; nj < 2; ++nj)
                ob[(size_t)o * L_ + col + nj * 16] =
                    (ushort_t)f2bf(acc[mi][nj][r] + bv);
        }
    }
}

// ---------------------------------------------------------------------------
// K2 fused: blockIdx.x in [0,64)  -> cm channel 64+s  (conv -> cm_bf)
//           blockIdx.x in [64,128)-> ab for s (conv dt -> softmax -> *conv Bm)
// ---------------------------------------------------------------------------
__global__ __launch_bounds__(256) void k2_conv(
    const ushort_t* __restrict__ pre, const float* __restrict__ wdw,
    const float* __restrict__ bdw, ushort_t* __restrict__ cm,
    ushort_t* __restrict__ ab)
{
    __shared__ float sm[66][66];
    __shared__ float red[4];
    const int t   = blockIdx.x;
    const int b   = blockIdx.y;
    const int s   = t & 63;
    const int tid = threadIdx.x;

    for (int i = tid; i < 66 * 66; i += 256) (&sm[0][0])[i] = 0.f;
    __syncthreads();

    if (t < 64) {
        const int c = 64 + s;
        const uint_t* ip32 = reinterpret_cast<const uint_t*>(
            pre + ((size_t)b * C3_ + c) * L_);
        for (int p2 = tid; p2 < 2048; p2 += 256) {
            uint_t v = ip32[p2];
            int q = p2 * 2;
            sm[(q >> 6) + 1][(q & 63) + 1] = bf2f((ushort_t)(v & 0xffffu));
            sm[(q >> 6) + 1][(q & 63) + 2] = bf2f((ushort_t)(v >> 16));
        }
        __syncthreads();
        const float* wp = wdw + c * 9;
        float w00 = wp[0], w01 = wp[1], w02 = wp[2],
              w10 = wp[3], w11 = wp[4], w12 = wp[5],
              w20 = wp[6], w21 = wp[7], w22 = wp[8];
        float bb = bdw[c];
        ushort_t* op = cm + ((size_t)b * S_ + s) * L_;
        for (int p = tid; p < 4096; p += 256) {
            int yy = p >> 6, xx = p & 63;
            float v = bb
                + sm[yy][xx] * w00     + sm[yy][xx + 1] * w01     + sm[yy][xx + 2] * w02
                + sm[yy + 1][xx] * w10 + sm[yy + 1][xx + 1] * w11 + sm[yy + 1][xx + 2] * w12
                + sm[yy + 2][xx] * w20 + sm[yy + 2][xx + 1] * w21 + sm[yy + 2][xx + 2] * w22;
            op[p] = (ushort_t)f2bf(v);
        }
        return;
    }

    const int cd = 128 + s;
    {
        const uint_t* ip32 = reinterpret_cast<const uint_t*>(
            pre + ((size_t)b * C3_ + cd) * L_);
        for (int p2 = tid; p2 < 2048; p2 += 256) {
            uint_t v = ip32[p2];
            int q = p2 * 2;
            sm[(q >> 6) + 1][(q & 63) + 1] = bf2f((ushort_t)(v & 0xffffu));
            sm[(q >> 6) + 1][(q & 63) + 2] = bf2f((ushort_t)(v >> 16));
        }
    }
    __syncthreads();
    float dt[16];
    {
        const float* wp = wdw + cd * 9;
        float w00 = wp[0], w01 = wp[1], w02 = wp[2],
              w10 = wp[3], w11 = wp[4], w12 = wp[5],
              w20 = wp[6], w21 = wp[7], w22 = wp[8];
        float bb = bdw[cd];
        #pragma unroll
        for (int i = 0; i < 16; ++i) {
            int p = tid + 256 * i;
            int yy = p >> 6, xx = p & 63;
            dt[i] = bb
                + sm[yy][xx] * w00     + sm[yy][xx + 1] * w01     + sm[yy][xx + 2] * w02
                + sm[yy + 1][xx] * w10 + sm[yy + 1][xx + 1] * w11 + sm[yy + 1][xx + 2] * w12
                + sm[yy + 2][xx] * w20 + sm[yy + 2][xx + 1] * w21 + sm[yy + 2][xx + 2] * w22;
        }
    }
    float mx = dt[0];
    #pragma unroll
    for (int i = 1; i < 16; ++i) mx = fmaxf(mx, dt[i]);
    #pragma unroll
    for (int off = 32; off >= 1; off >>= 1) mx = fmaxf(mx, __shfl_xor(mx, off, 64));
    if ((tid & 63) == 0) red[tid >> 6] = mx;
    __syncthreads();
    mx = fmaxf(fmaxf(red[0], red[1]), fmaxf(red[2], red[3]));
    float e[16];
    float lsum = 0.f;
    #pragma unroll
    for (int i = 0; i < 16; ++i) { e[i] = expf(dt[i] - mx); lsum += e[i]; }
    #pragma unroll
    for (int off = 32; off >= 1; off >>= 1) lsum += __shfl_xor(lsum, off, 64);
    __syncthreads();
    if ((tid & 63) == 0) red[tid >> 6] = lsum;
    __syncthreads();
    const float inv = 1.f / (red[0] + red[1] + red[2] + red[3]);
    {
        const uint_t* ip32 = reinterpret_cast<const uint_t*>(
            pre + ((size_t)b * C3_ + s) * L_);
        for (int p2 = tid; p2 < 2048; p2 += 256) {
            uint_t v = ip32[p2];
            int q = p2 * 2;
            sm[(q >> 6) + 1][(q & 63) + 1] = bf2f((ushort_t)(v & 0xffffu));
            sm[(q >> 6) + 1][(q & 63) + 2] = bf2f((ushort_t)(v >> 16));
        }
    }
    __syncthreads();
    {
        const float* wp = wdw + s * 9;
        float w00 = wp[0], w01 = wp[1], w02 = wp[2],
              w10 = wp[3], w11 = wp[4], w12 = wp[5],
              w20 = wp[6], w21 = wp[7], w22 = wp[8];
        float bb = bdw[s];
        ushort_t* op = ab + ((size_t)b * S_ + s) * L_;
        #pragma unroll
        for (int i = 0; i < 16; ++i) {
            int p = tid + 256 * i;
            int yy = p >> 6, xx = p & 63;
            float bm = bb
                + sm[yy][xx] * w00     + sm[yy][xx + 1] * w01     + sm[yy][xx + 2] * w02
                + sm[yy + 1][xx] * w10 + sm[yy + 1][xx + 1] * w11 + sm[yy + 1][xx + 2] * w12
                + sm[yy + 2][xx] * w20 + sm[yy + 2][xx + 1] * w21 + sm[yy + 2][xx + 2] * w22;
            op[p] = (ushort_t)f2bf(e[i] * inv * bm);
        }
    }
}

// ---------------------------------------------------------------------------
// K3 (MFMA, no LDS): hp[chunk][b][d][s] += xbf[b,d,l]*ab[b,s,l] over l-chunk 512
// Both operands bf16 + l(K)-contiguous -> pure 16-B frag loads, zero cvt.
// ---------------------------------------------------------------------------
__global__ __launch_bounds__(256) void k3_hpart_mfma(
    const ushort_t* __restrict__ xbf, const ushort_t* __restrict__ ab,
    float* __restrict__ hp)
{
    const int dt    = blockIdx.x;   // 0..1
    const int b     = blockIdx.y;   // 0..31
    const int chunk = blockIdx.z;   // 0..NCHUNK-1
    const int tid  = threadIdx.x;
    const int lane = tid & 63;
    const int wv   = tid >> 6;
    const int wr   = wv >> 1, wc = wv & 1;
    const int lm   = lane & 15, kg = lane >> 4;
    const int d_base = dt * 128 + wr * 64;
    const int s_base = wc * 32;
    const ushort_t* xbb = xbf + (size_t)b * D_ * L_;
    const ushort_t* abb = ab  + (size_t)b * S_ * L_;

    f32x4 acc[4][2];
    #pragma unroll
    for (int mi = 0; mi < 4; ++mi)
        #pragma unroll
        for (int nj = 0; nj < 2; ++nj)
            acc[mi][nj] = (f32x4){0.f, 0.f, 0.f, 0.f};

    #pragma unroll 2
    for (int ks = 0; ks < 16; ++ks) {
        const int l = chunk * 512 + ks * 32 + kg * 8;
        short8 bfr[2];
        #pragma unroll
        for (int nj = 0; nj < 2; ++nj)
            bfr[nj] = *reinterpret_cast<const short8*>(
                abb + (size_t)(s_base + nj * 16 + lm) * L_ + l);
        #pragma unroll
        for (int mi = 0; mi < 4; ++mi) {
            short8 a = *reinterpret_cast<const short8*>(
                xbb + (size_t)(d_base + mi * 16 + lm) * L_ + l);
            #pragma unroll
            for (int nj = 0; nj < 2; ++nj)
                acc[mi][nj] = __builtin_amdgcn_mfma_f32_16x16x32_bf16(
                    a, bfr[nj], acc[mi][nj], 0, 0, 0);
        }
    }
    float* hpo = hp + (size_t)chunk * HOUTSZ + (size_t)b * D_ * S_;
    #pragma unroll
    for (int mi = 0; mi < 4; ++mi)
        #pragma unroll
        for (int r = 0; r < 4; ++r) {
            int d = d_base + mi * 16 + kg * 4 + r;
            #pragma unroll
            for (int nj = 0; nj < 2; ++nj)
                hpo[(size_t)d * S_ + s_base + nj * 16 + lm] = acc[mi][nj][r];
        }
}

// ---------------------------------------------------------------------------
// K4a: h = sum_chunk hp (fused); hz = w_hz @ h + b_hz; g = h2*(silu(z)+D)
// ---------------------------------------------------------------------------
__global__ __launch_bounds__(256) void k4a_gate(
    const float* __restrict__ hp, const float* __restrict__ whz,
    const float* __restrict__ bhz, const float* __restrict__ Dp,
    float* __restrict__ g)
{
    __shared__ float Ah[16][68];
    __shared__ float Az[16][68];
    __shared__ float Bs[16][64];
    const int o0 = blockIdx.x * 64;
    const int b  = blockIdx.y;
    const int tid = threadIdx.x;
    const int tx = tid & 15, ty = tid >> 4;
    float acch[4][4] = {}, accz[4][4] = {};
    const float* hb = hp + (size_t)b * D_ * S_;
    for (int k0 = 0; k0 < D_; k0 += 16) {
        {
            int o = tid & 15, k = tid >> 4;
            #pragma unroll
            for (int i = 0; i < 4; ++i) {
                Ah[k][o + 16 * i] = whz[(size_t)(o0 + o + 16 * i) * D_ + k0 + k];
                Az[k][o + 16 * i] = whz[(size_t)(o0 + o + 16 * i + 256) * D_ + k0 + k];
            }
        }
        {
            int s = tid & 63, k = tid >> 6;
            #pragma unroll
            for (int i = 0; i < 4; ++i) {
                float sum = 0.f;
                #pragma unroll
                for (int c = 0; c < NCHUNK; ++c)
                    sum += hb[(size_t)c * HOUTSZ + (size_t)(k0 + k + 4 * i) * S_ + s];
                Bs[k + 4 * i][s] = sum;
            }
        }
        __syncthreads();
        #pragma unroll
        for (int k = 0; k < 16; ++k) {
            float ah[4], az[4], bb[4];
            #pragma unroll
            for (int i = 0; i < 4; ++i) { ah[i] = Ah[k][ty * 4 + i]; az[i] = Az[k][ty * 4 + i]; }
            #pragma unroll
            for (int j = 0; j < 4; ++j) bb[j] = Bs[k][tx * 4 + j];
            #pragma unroll
            for (int i = 0; i < 4; ++i)
                #pragma unroll
                for (int j = 0; j < 4; ++j) {
                    acch[i][j] += ah[i] * bb[j];
                    accz[i][j] += az[i] * bb[j];
                }
        }
        __syncthreads();
    }
    const float dp = Dp[0];
    #pragma unroll
    for (int i = 0; i < 4; ++i) {
        int o = o0 + ty * 4 + i;
        float bh = bhz[o], bz = bhz[o + 256];
        #pragma unroll
        for (int j = 0; j < 4; ++j) {
            float h2 = acch[i][j] + bh;
            float z  = accz[i][j] + bz;
            float sil = z / (1.f + expf(-z));
            g[((size_t)b * D_ + o) * S_ + tx * 4 + j] = h2 * (sil + dp);
        }
    }
}

// ---------------------------------------------------------------------------
// K4b: hout = w_out @ g + b_out -> d_out (output 1)
// ---------------------------------------------------------------------------
__global__ __launch_bounds__(256) void k4b_hout(
    const float* __restrict__ g, const float* __restrict__ wout,
    const float* __restrict__ bout, float* __restrict__ hout)
{
    __shared__ float At[16][68];
    __shared__ float Bs[16][64];
    const int o0 = blockIdx.x * 64;
    const int b  = blockIdx.y;
    const int tid = threadIdx.x;
    const int tx = tid & 15, ty = tid >> 4;
    float acc[4][4] = {};
    const float* gb = g + (size_t)b * D_ * S_;
    for (int k0 = 0; k0 < D_; k0 += 16) {
        {
            int o = tid & 15, k = tid >> 4;
            #pragma unroll
            for (int i = 0; i < 4; ++i)
                At[k][o + 16 * i] = wout[(size_t)(o0 + o + 16 * i) * D_ + k0 + k];
        }
        {
            int s = tid & 63, k = tid >> 6;
            #pragma unroll
            for (int i = 0; i < 4; ++i)
                Bs[k + 4 * i][s] = gb[(size_t)(k0 + k + 4 * i) * S_ + s];
        }
        __syncthreads();
        #pragma unroll
        for (int k = 0; k < 16; ++k) {
            float a[4], bb[4];
            #pragma unroll
            for (int i = 0; i < 4; ++i) a[i] = At[k][ty * 4 + i];
            #pragma unroll
            for (int j = 0; j < 4; ++j) bb[j] = Bs[k][tx * 4 + j];
            #pragma unroll
            for (int i = 0; i < 4; ++i)
                #pragma unroll
                for (int j = 0; j < 4; ++j)
                    acc[i][j] += a[i] * bb[j];
        }
        __syncthreads();
    }
    #pragma unroll
    for (int i = 0; i < 4; ++i) {
        int o = o0 + ty * 4 + i;
        float bv = bout[o];
        #pragma unroll
        for (int j = 0; j < 4; ++j)
            hout[((size_t)b * D_ + o) * S_ + tx * 4 + j] = acc[i][j] + bv;
    }
}

// ---------------------------------------------------------------------------
// K5 (MFMA): y[b][d][l] = sum_s hout[b][d][s] * cm_bf[b][s][l]
// ---------------------------------------------------------------------------
__global__ __launch_bounds__(256) void k5_expand_mfma(
    const float* __restrict__ hout, const ushort_t* __restrict__ cm,
    float* __restrict__ y)
{
    __shared__ __align__(16) short A_lds[64][72];   // [d][s]
    __shared__ __align__(16) short B_lds[128][72];  // [l][s]
    const int l0 = blockIdx.x * 128;
    const int d0 = blockIdx.y * 64;
    const int b  = blockIdx.z;
    const int tid  = threadIdx.x;
    const int lane = tid & 63;
    const int wv   = tid >> 6;
    const int lm   = lane & 15, kg = lane >> 4;

    #pragma unroll
    for (int q = 0; q < 2; ++q) {
        int task = q * 256 + tid;
        int d = task >> 3, sg = (task & 7) * 8;
        *(short8*)&A_lds[d][sg] = ld_cvt8(hout + ((size_t)b * D_ + d0 + d) * S_ + sg);
    }
    #pragma unroll
    for (int q = 0; q < 4; ++q) {
        int l = tid & 127;
        int sg = (q * 2 + (tid >> 7)) * 8;
        const ushort_t* cp = cm + ((size_t)b * S_ + sg) * L_ + l0 + l;
        short8 s;
        #pragma unroll
        for (int r = 0; r < 8; ++r) s[r] = (short)cp[(size_t)r * L_];
        *(short8*)&B_lds[l][sg] = s;
    }
    __syncthreads();

    f32x4 acc[4][2];
    #pragma unroll
    for (int mi = 0; mi < 4; ++mi)
        #pragma unroll
        for (int nj = 0; nj < 2; ++nj)
            acc[mi][nj] = (f32x4){0.f, 0.f, 0.f, 0.f};
    #pragma unroll
    for (int ks = 0; ks < 2; ++ks) {
        short8 bb[2];
        #pragma unroll
        for (int nj = 0; nj < 2; ++nj)
            bb[nj] = *(const short8*)&B_lds[wv * 32 + nj * 16 + lm][ks * 32 + kg * 8];
        #pragma unroll
        for (int mi = 0; mi < 4; ++mi) {
            short8 a = *(const short8*)&A_lds[mi * 16 + lm][ks * 32 + kg * 8];
            #pragma unroll
            for (int nj = 0; nj < 2; ++nj)
                acc[mi][nj] = __builtin_amdgcn_mfma_f32_16x16x32_bf16(
                    a, bb[nj], acc[mi][nj], 0, 0, 0);
        }
    }
    const int col = l0 + wv * 32 + lm;
    #pragma unroll
    for (int mi = 0; mi < 4; ++mi)
        #pragma unroll
        for (int r = 0; r < 4; ++r)
            #pragma unroll
            for (int nj = 0; nj < 2; ++nj)
                y[((size_t)b * D_ + d0 + mi * 16 + kg * 4 + r) * L_ + col + nj * 16]
                    = acc[mi][nj][r];
}

// ---------------------------------------------------------------------------
extern "C" void kernel_launch(void* const* d_in, const int* in_sizes, int n_in,
                              void* d_out, int out_size, void* d_ws, size_t ws_size,
                              hipStream_t stream)
{
    const float* x      = (const float*)d_in[0];
    const float* w_bcdt = (const float*)d_in[3];
    const float* b_bcdt = (const float*)d_in[4];
    const float* w_dw   = (const float*)d_in[5];
    const float* b_dw   = (const float*)d_in[6];
    const float* w_hz   = (const float*)d_in[7];
    const float* b_hz   = (const float*)d_in[8];
    const float* w_out  = (const float*)d_in[9];
    const float* b_out  = (const float*)d_in[10];
    // d_in[11] = A_param: constant along softmax axis L -> cancels, unused
    const float* Dp     = (const float*)d_in[12];

    char* base = (char*)d_ws;
    ushort_t* pre_bf = (ushort_t*)(base);                  // 50.3 MB (dead after k2)
    ushort_t* xbf    = (ushort_t*)(base + 50331648);       // 67.1 MB
    ushort_t* ab_bf  = (ushort_t*)(base + 117440512);      // 16.8 MB
    ushort_t* cm_bf  = (ushort_t*)(base + 134217728);      // 16.8 MB
    float*    hp     = (float*)   (base);                  // reuse pre: 16.8 MB
    float*    g      = (float*)   (base + 16777216);       //  2.1 MB (in pre region)
    ushort_t* wfrag  = (ushort_t*)(base + 150994944);      //  0.1 MB

    float* y    = (float*)d_out;
    float* hout = (float*)d_out + YSZ;

    k0_wfrag      <<<24,                  256, 0, stream>>>(w_bcdt, wfrag);
    k1_bcdt_mfma  <<<dim3(32, 32),        256, 0, stream>>>(x, wfrag, b_bcdt, pre_bf, xbf);
    k2_conv       <<<dim3(128, 32),       256, 0, stream>>>(pre_bf, w_dw, b_dw, cm_bf, ab_bf);
    k3_hpart_mfma <<<dim3(2, 32, NCHUNK), 256, 0, stream>>>(xbf, ab_bf, hp);
    k4a_gate      <<<dim3(4, 32),         256, 0, stream>>>(hp, w_hz, b_hz, Dp, g);
    k4b_hout      <<<dim3(4, 32),         256, 0, stream>>>(g, w_out, b_out, hout);
    k5_expand_mfma<<<dim3(32, 4, 32),     256, 0, stream>>>(hout, cm_bf, y);
}